// Round 10
// baseline (23253.876 us; speedup 1.0000x reference)
//
#include <hip/hip_runtime.h>
#include <hip/hip_bf16.h>

// ---------------------------------------------------------------------------
// Decoder (Tacotron-style) on MI355X. Round 10: 2 batches per block,
// LDS reduced to the proven envelope (<=135KB vs r8's 155KB).
// r8/r9 both died in infra ("container failed twice", never ran). The only
// out-of-envelope property of that source was 155KB static LDS (proven max
// 132KB). This round: same 2-batch design, GRU hh-partials overlaid into
// cbuf (dead between R8 and next R3), scrA/scrB 6144->4096 floats.
// Numerics and stage structure identical to the r8 design.
//
// Hypothesis under test (r0-r7 accounting): per-CU weight streaming is the
// wall — 64 blocks each pull the SAME 3.7MB/step of f16 weights at ~30GB/s
// effective (~110us stall/step) while VALU is only ~32us. Amortize the
// stream across 2 batches per block: each GEMV thread loads a row once,
// dots against both batches (2nd chain = free ILP under load latency).
// -> 32 blocks, per-batch weight bytes halved, per-batch order unchanged.
// ---------------------------------------------------------------------------

typedef unsigned int u32;

#ifndef __has_builtin
#define __has_builtin(x) 0
#endif

#define NSTEP 100

// workspace offsets in 4-byte units
#define PK_ATTIH 0                      // 320*768
#define PK_ATTHH 245760                 // 128*768
#define PK_Q     344064                 // 128*128
#define PK_PD    360448                 // 384*256
#define PK_D1IH  458752                 // 128*768
#define PK_D1HH  557056
#define PK_D2IH  655360
#define PK_D2HH  753664
#define PK_MEL   851968                 // 128*560
#define W1T_U    923648                 // 80*256 fp32
#define W2T_U    944128                 // 256*128 fp32
#define PROCF_U  976896                 // half[64*512*128] = 2097152 u32
#define P2ALL_U  3074048                // float[100*64*128] = 819200
#define INPT_U   3893248                // temp 128*512 fp32; lcgT after proc
#define MSTG_U   3958784                // float[64*100*560] = 3584000
#define INF16_U  7542784                // half[64*512*512] = 8388608 u32
#define WS_NEED_U 15931392              // u32 needed for big path (validated)

#define OUT_ATT  3584000
#define OUT_STOP 6860800

typedef _Float16 h2 __attribute__((ext_vector_type(2)));
typedef float f32x4 __attribute__((ext_vector_type(4)));
typedef unsigned int u32x4 __attribute__((ext_vector_type(4)));
union U4 { uint4 v; _Float16 h[8]; };

__device__ __forceinline__ float fastrcp(float x) { return __builtin_amdgcn_rcpf(x); }
__device__ __forceinline__ float sig_p(float x) { return 1.f / (1.f + __expf(-x)); }
__device__ __forceinline__ float tanh_f(float x) {
    x = fminf(fmaxf(x, -15.f), 15.f);
    float e2 = __expf(2.f * x);
    return (e2 - 1.f) * fastrcp(e2 + 1.f);
}

__device__ __forceinline__ float dot2(u32 w, u32 x, float acc) {
    h2 wh = __builtin_bit_cast(h2, w);
    h2 xh = __builtin_bit_cast(h2, x);
#if __has_builtin(__builtin_amdgcn_fdot2)
    return __builtin_amdgcn_fdot2(wh, xh, acc, false);
#else
    return acc + (float)wh.x * (float)xh.x + (float)wh.y * (float)xh.y;
#endif
}

__device__ __forceinline__ u32 packh2(float a, float b) {
    h2 h; h.x = (_Float16)a; h.y = (_Float16)b;
    return __builtin_bit_cast(u32, h);
}

__device__ __forceinline__ float4 ntload_f4(const float* p) {
    f32x4 v = __builtin_nontemporal_load((const f32x4*)p);
    float4 r; r.x = v.x; r.y = v.y; r.z = v.z; r.w = v.w; return r;
}
__device__ __forceinline__ uint4 ntload_u4(const uint4* p) {
    u32x4 v = __builtin_nontemporal_load((const u32x4*)p);
    uint4 r; r.x = v.x; r.y = v.y; r.z = v.z; r.w = v.w; return r;
}
__device__ __forceinline__ float ntload_f(const float* p) {
    return __builtin_nontemporal_load(p);
}
__device__ __forceinline__ void ntstore_f(float* p, float v) {
    __builtin_nontemporal_store(v, p);
}

// transpose: src (O x K) row-major -> dst (K x O)
__global__ void tkern(const float* __restrict__ src, float* __restrict__ dst, int O, int K) {
    int i = blockIdx.x * blockDim.x + threadIdx.x;
    if (i < O * K) {
        int o = i % O, k = i / O;
        dst[i] = src[o * K + k];
    }
}

// pack fp32 (O x K) -> f16 pairs: dst[(k/2)*O + o] = (w[o][2p], w[o][2p+1])
__global__ void packw(const float* __restrict__ src, u32* __restrict__ dst, int O, int K) {
    int i = blockIdx.x * blockDim.x + threadIdx.x;
    int n = O * (K >> 1);
    if (i < n) {
        int o = i % O, p = i / O;
        dst[i] = packh2(src[o * K + 2 * p], src[o * K + 2 * p + 1]);
    }
}

// pack inputs fp32 -> f16 pairs (same element order)
__global__ void packi(const float* __restrict__ src, u32* __restrict__ dst) {
    int i = blockIdx.x * blockDim.x + threadIdx.x;
    if (i < 8388608) dst[i] = packh2(src[2 * i], src[2 * i + 1]);
}

// loc_conv (32 x 2 x 31) -> transposed f32 [ch*31+k][c] (global table)
__global__ void tlcg(const float* __restrict__ lcg, float* __restrict__ dst) {
    int i = blockIdx.x * blockDim.x + threadIdx.x;
    if (i < 1984) { int k = i >> 5, c = i & 31; dst[i] = lcg[c * 62 + k]; }
}

// mel staging [b][step][o=jj*80+mm] -> out [b][mm][7*step+jj]
__global__ void unmel(const float* __restrict__ ms, float* __restrict__ out) {
    int i = blockIdx.x * blockDim.x + threadIdx.x;
    if (i < 3584000) {
        int b = i / 56000, r = i % 56000;
        int mm = r / 700, c = r % 700;
        int step = c / 7, jj = c % 7;
        out[i] = ms[((size_t)b * 100 + step) * 560 + jj * 80 + mm];
    }
}

__global__ void prenet_kern(const float* __restrict__ memory,
                            const float* __restrict__ w1T, const float* __restrict__ b1,
                            const float* __restrict__ w2T, const float* __restrict__ b2,
                            float* __restrict__ p2all) {
    __shared__ float mi[80];
    __shared__ float p1[256];
    int blk = blockIdx.x;
    int t = blk >> 6, b = blk & 63;
    int tid = threadIdx.x;
    if (tid < 80) mi[tid] = (t == 0) ? 0.f : memory[(b * 700 + (7 * t - 1)) * 80 + tid];
    __syncthreads();
    float acc = b1[tid];
#pragma unroll 4
    for (int k = 0; k < 80; k++) acc += mi[k] * w1T[k * 256 + tid];
    p1[tid] = fmaxf(acc, 0.f);
    __syncthreads();
    if (tid < 128) {
        float a2 = b2[tid];
#pragma unroll 4
        for (int k = 0; k < 256; k++) a2 += p1[k] * w2T[k * 128 + tid];
        p2all[(t * 64 + b) * 128 + tid] = fmaxf(a2, 0.f);
    }
}

// proc_in -> f16, layout [b][t][a]
__global__ void proc_kern(const float* __restrict__ inputs, const float* __restrict__ inpT,
                          _Float16* __restrict__ procF) {
    __shared__ float xin[8][512];
    int blk = blockIdx.x;
    int b = blk >> 6, t0 = (blk & 63) << 3;
    int tid = threadIdx.x;
    for (int i = tid; i < 8 * 512; i += 1024)
        xin[i >> 9][i & 511] = inputs[((size_t)b * 512 + t0 + (i >> 9)) * 512 + (i & 511)];
    __syncthreads();
    int r = tid >> 7, a = tid & 127;
    float acc = 0.f;
#pragma unroll 4
    for (int d = 0; d < 512; d++) acc += xin[r][d] * inpT[d * 128 + a];
    procF[((size_t)(b * 512) + t0 + r) * 128 + a] = (_Float16)acc;
}

__launch_bounds__(1024, 1)
__global__ void decoder_kern(const float* __restrict__ inputs,
                             const u32* __restrict__ wsu,
                             const float* __restrict__ att_b_ih, const float* __restrict__ att_b_hh,
                             const float* __restrict__ v_w, const float* __restrict__ v_b,
                             const float* __restrict__ lcgTg, const float* __restrict__ lwg,
                             const float* __restrict__ pd_b,
                             const float* __restrict__ d1b_ih, const float* __restrict__ d1b_hh,
                             const float* __restrict__ d2b_ih, const float* __restrict__ d2b_hh,
                             const float* __restrict__ mel_b,
                             const float* __restrict__ stop_w, const float* __restrict__ stop_b,
                             float* __restrict__ out, int big) {
    const int blk = blockIdx.x;          // 0..31; batches 2*blk, 2*blk+1
    const int tid = threadIdx.x;

    const uint4* w_attih = (const uint4*)(wsu + PK_ATTIH);
    const uint4* w_atthh = (const uint4*)(wsu + PK_ATTHH);
    const uint4* w_pd    = (const uint4*)(wsu + PK_PD);
    const uint4* w_d1ih  = (const uint4*)(wsu + PK_D1IH);
    const uint4* w_d1hh  = (const uint4*)(wsu + PK_D1HH);
    const uint4* w_d2ih  = (const uint4*)(wsu + PK_D2IH);
    const uint4* w_d2hh  = (const uint4*)(wsu + PK_D2HH);
    const uint4* w_mel   = (const uint4*)(wsu + PK_MEL);
    const _Float16* procF = (const _Float16*)(wsu + PROCF_U);
    const float* p2all   = (const float*)(wsu + P2ALL_U);
    const _Float16* inF16 = (const _Float16*)(wsu + INF16_U);
    float* mstage        = (float*)(wsu + MSTG_U);

    // per-batch state: [bt] index throughout (bt=0 -> batch 2*blk, bt=1 -> +1)
    __shared__ float h_att[512], h1[512], h2[512], dec[512];
    __shared__ float awp[1084], awcp[1084];            // [bt*542 + ...]
    __shared__ __align__(16) float pqv[512];           // [bt*256 + 2a] = {pq, v_w}
    __shared__ float red[32], mout[1120];
    // cbuf overlays (all uses fenced by barriers, each dead before reuse):
    //  - R1/R11/R13: hh partials, float[bt*3072 + ks*768 + og*4] (read R2/R12/R14)
    //  - R3: conv f16 c-pairs, u32[bt*8208 + cp*513 + tp]        (read R5)
    //  - R7: ctx f32 partials, float[bt*4096 + ...]              (read R8)
    __shared__ __align__(16) u32 cbuf[2 * 16 * 513];
    __shared__ __align__(16) float scrA[4096];         // b0 ih/pd/mel partials; energies
    __shared__ __align__(16) float scrB[4096];         // b1 ih/pd/mel partials
    __shared__ u32 xpatt[640];   // [bt*320 + (p2 0..63 | ctx 64..319)]
    __shared__ u32 xppd[768];    // [bt*384 + (h_att 0..127 | ctx 128..383)]
    __shared__ u32 decp[256], h1p[256], h2p[256];      // [bt*128 + ...]
    __shared__ __align__(16) u32 lwp_lds[128 * 16];    // lwg f16 c-pairs [a][cp]

    float* scrH = (float*)cbuf;          // hh-partials overlay

    for (int i = tid; i < 512; i += 1024) { h_att[i] = 0.f; h1[i] = 0.f; h2[i] = 0.f; dec[i] = 0.f; }
    for (int i = tid; i < 1084; i += 1024) { awp[i] = 0.f; awcp[i] = 0.f; }
    for (int i = tid; i < 640; i += 1024) xpatt[i] = 0u;
    for (int i = tid; i < 768; i += 1024) xppd[i] = 0u;
    if (tid < 256) { decp[tid] = 0u; h1p[tid] = 0u; h2p[tid] = 0u; }
    for (int i = tid; i < 2048; i += 1024)
        lwp_lds[i] = packh2(lwg[2 * i], lwg[2 * i + 1]);
    if (tid < 256) { pqv[2 * tid] = 0.f; pqv[2 * tid + 1] = v_w[tid & 127]; }
    if (tid >= 960) {   // pack p2 for step 0, both batches
        int j = tid - 960;
        const float* p20 = p2all + (size_t)(blk * 2) * 128;
        xpatt[j]       = packh2(p20[2 * j], p20[2 * j + 1]);
        xpatt[320 + j] = packh2(p20[128 + 2 * j], p20[128 + 2 * j + 1]);
    }
    const float vb0 = v_b[0];
    const float sb0 = stop_b[0];
    __syncthreads();

    for (int step = 0; step < NSTEP; step++) {
        // ---- R1: att-GRU gate partials, both batches (768 thr) ----
        if (tid < 768) {
            const int og = tid % 192;
            const int ks = tid / 192;
            float4 ai0 = {0.f,0.f,0.f,0.f}, ai1 = {0.f,0.f,0.f,0.f};
            float4 ah0 = {0.f,0.f,0.f,0.f}, ah1 = {0.f,0.f,0.f,0.f};
#pragma unroll 8
            for (int p = ks * 80; p < ks * 80 + 80; p++) {
                uint4 w = w_attih[p * 192 + og];
                u32 x0 = xpatt[p], x1 = xpatt[320 + p];
                ai0.x = dot2(w.x, x0, ai0.x); ai0.y = dot2(w.y, x0, ai0.y);
                ai0.z = dot2(w.z, x0, ai0.z); ai0.w = dot2(w.w, x0, ai0.w);
                ai1.x = dot2(w.x, x1, ai1.x); ai1.y = dot2(w.y, x1, ai1.y);
                ai1.z = dot2(w.z, x1, ai1.z); ai1.w = dot2(w.w, x1, ai1.w);
            }
#pragma unroll 8
            for (int p = ks * 32; p < ks * 32 + 32; p++) {
                uint4 w = w_atthh[p * 192 + og];
                u32 x0 = xppd[p], x1 = xppd[384 + p];
                ah0.x = dot2(w.x, x0, ah0.x); ah0.y = dot2(w.y, x0, ah0.y);
                ah0.z = dot2(w.z, x0, ah0.z); ah0.w = dot2(w.w, x0, ah0.w);
                ah1.x = dot2(w.x, x1, ah1.x); ah1.y = dot2(w.y, x1, ah1.y);
                ah1.z = dot2(w.z, x1, ah1.z); ah1.w = dot2(w.w, x1, ah1.w);
            }
            *(float4*)&scrA[ks * 768 + og * 4] = ai0;
            *(float4*)&scrB[ks * 768 + og * 4] = ai1;
            *(float4*)&scrH[ks * 768 + og * 4] = ah0;
            *(float4*)&scrH[3072 + ks * 768 + og * 4] = ah1;
        }
        __syncthreads();

        // ---- R2: att-GRU combine (256 thr = 2 bt x 128) ----
        if (tid < 256) {
            const int bt = tid >> 7, lo = tid & 127;
            const float* P = bt ? scrB : scrA;
            const float* H = scrH + bt * 3072;
            float hv[2];
#pragma unroll
            for (int j = 0; j < 2; j++) {
                const int o = lo * 2 + j;
                float gr = att_b_ih[o], gz = att_b_ih[256 + o], gn = att_b_ih[512 + o];
                float hr = att_b_hh[o], hz = att_b_hh[256 + o], hn = att_b_hh[512 + o];
#pragma unroll
                for (int s = 0; s < 4; s++) {
                    gr += P[s * 768 + o]; gz += P[s * 768 + 256 + o]; gn += P[s * 768 + 512 + o];
                    hr += H[s * 768 + o]; hz += H[s * 768 + 256 + o]; hn += H[s * 768 + 512 + o];
                }
                float r = sig_p(gr + hr), z = sig_p(gz + hz);
                float n = tanh_f(gn + r * hn);
                hv[j] = (1.f - z) * n + z * h_att[bt * 256 + o];
                h_att[bt * 256 + o] = hv[j];
            }
            xppd[bt * 384 + lo] = packh2(hv[0], hv[1]);
        }
        __syncthreads();

        // ---- R3: q (256 thr, both bt) || conv (768 thr, 1024 positions) ----
        if (tid < 256) {
            const int bt = tid >> 7, a = tid & 127;
            const u32* wqu = wsu + PK_Q;
            const u32* xp = xppd + bt * 384;
            float qa = 0.f;
#pragma unroll 8
            for (int p = 0; p < 128; p++) qa = dot2(wqu[p * 128 + a], xp[p], qa);
            pqv[bt * 256 + 2 * a] = qa;
        } else {
            auto conv_one = [&](int idx) {
                const int bt = idx >> 9, tp = idx & 511;
                float cr[32];
#pragma unroll
                for (int c = 0; c < 32; c++) cr[c] = 0.f;
#pragma clang loop unroll_count(2)
                for (int k = 0; k < 31; k++) {
                    float a1 = awp[bt * 542 + tp + k], a2 = awcp[bt * 542 + tp + k];
                    const float4* l1 = (const float4*)&lcgTg[k * 32];
                    const float4* l2 = (const float4*)&lcgTg[(31 + k) * 32];
#pragma unroll
                    for (int cc = 0; cc < 8; cc++) {
                        float4 w1 = l1[cc], w2 = l2[cc];
                        cr[4 * cc]     += w1.x * a1 + w2.x * a2;
                        cr[4 * cc + 1] += w1.y * a1 + w2.y * a2;
                        cr[4 * cc + 2] += w1.z * a1 + w2.z * a2;
                        cr[4 * cc + 3] += w1.w * a1 + w2.w * a2;
                    }
                }
#pragma unroll
                for (int cp = 0; cp < 16; cp++)
                    cbuf[bt * 8208 + cp * 513 + tp] = packh2(cr[2 * cp], cr[2 * cp + 1]);
            };
            const int j = tid - 256;       // 0..767
            conv_one(j);
            if (j < 256) conv_one(j + 768);
        }
        __syncthreads();

        // ---- R5: attention energies. 16 waves = bt(2) x tg(4) x ag(2);
        //          2 t/lane, 64 a/wave; lw from LDS, procF nt ----
        {
            const int wv = tid >> 6, lane = tid & 63;
            const int bt = wv >> 3, w8 = wv & 7;
            const int tg = w8 & 3, ag = w8 >> 2;
            const int a0 = ag << 6;
            const int t0 = (tg << 7) + lane;        // and t0+64
            u32 crA[16], crB[16];
#pragma unroll
            for (int cp = 0; cp < 16; cp++) {
                crA[cp] = cbuf[bt * 8208 + cp * 513 + t0];
                crB[cp] = cbuf[bt * 8208 + cp * 513 + t0 + 64];
            }
            const uint4* pfA = (const uint4*)(procF + ((size_t)((blk * 2 + bt) * 512 + t0)) * 128 + a0);
            const uint4* pfB = (const uint4*)(procF + ((size_t)((blk * 2 + bt) * 512 + t0 + 64)) * 128 + a0);
            float acc0 = 0.f, acc1 = 0.f;
#pragma unroll
            for (int l = 0; l < 8; l++) {
                U4 uA; uA.v = ntload_u4(pfA + l);
                U4 uB; uB.v = ntload_u4(pfB + l);
#pragma unroll
                for (int j = 0; j < 8; j++) {
                    const int a = a0 + l * 8 + j;
                    float2 pv = *(const float2*)&pqv[bt * 256 + 2 * a];
                    const uint4* lw = (const uint4*)&lwp_lds[a * 16];
                    uint4 w0 = lw[0], w1 = lw[1], w2 = lw[2], w3 = lw[3];
                    float s0 = pv.x + (float)uA.h[j];
                    float s1 = pv.x + (float)uB.h[j];
                    s0 = dot2(w0.x, crA[0], s0);  s1 = dot2(w0.x, crB[0], s1);
                    s0 = dot2(w0.y, crA[1], s0);  s1 = dot2(w0.y, crB[1], s1);
                    s0 = dot2(w0.z, crA[2], s0);  s1 = dot2(w0.z, crB[2], s1);
                    s0 = dot2(w0.w, crA[3], s0);  s1 = dot2(w0.w, crB[3], s1);
                    s0 = dot2(w1.x, crA[4], s0);  s1 = dot2(w1.x, crB[4], s1);
                    s0 = dot2(w1.y, crA[5], s0);  s1 = dot2(w1.y, crB[5], s1);
                    s0 = dot2(w1.z, crA[6], s0);  s1 = dot2(w1.z, crB[6], s1);
                    s0 = dot2(w1.w, crA[7], s0);  s1 = dot2(w1.w, crB[7], s1);
                    s0 = dot2(w2.x, crA[8], s0);  s1 = dot2(w2.x, crB[8], s1);
                    s0 = dot2(w2.y, crA[9], s0);  s1 = dot2(w2.y, crB[9], s1);
                    s0 = dot2(w2.z, crA[10], s0); s1 = dot2(w2.z, crB[10], s1);
                    s0 = dot2(w2.w, crA[11], s0); s1 = dot2(w2.w, crB[11], s1);
                    s0 = dot2(w3.x, crA[12], s0); s1 = dot2(w3.x, crB[12], s1);
                    s0 = dot2(w3.y, crA[13], s0); s1 = dot2(w3.y, crB[13], s1);
                    s0 = dot2(w3.z, crA[14], s0); s1 = dot2(w3.z, crB[14], s1);
                    s0 = dot2(w3.w, crA[15], s0); s1 = dot2(w3.w, crB[15], s1);
                    acc0 += pv.y * tanh_f(s0);
                    acc1 += pv.y * tanh_f(s1);
                }
            }
            scrA[bt * 1024 + ag * 512 + t0] = acc0;
            scrA[bt * 1024 + ag * 512 + t0 + 64] = acc1;
        }
        __syncthreads();

        // ---- R6: softmax per batch (both halves concurrently, 3 barriers) ----
        {
            const int bt = tid >> 9, t = tid & 511;
            float e_reg = scrA[bt * 1024 + t] + scrA[bt * 1024 + 512 + t] + vb0;
            float v = e_reg;
#pragma unroll
            for (int off = 32; off; off >>= 1) v = fmaxf(v, __shfl_down(v, off, 64));
            if ((tid & 63) == 0) red[tid >> 6] = v;
            __syncthreads();
            float smax = fmaxf(fmaxf(fmaxf(red[bt*8+0], red[bt*8+1]), fmaxf(red[bt*8+2], red[bt*8+3])),
                               fmaxf(fmaxf(red[bt*8+4], red[bt*8+5]), fmaxf(red[bt*8+6], red[bt*8+7])));
            float ex = __expf(e_reg - smax);
            v = ex;
#pragma unroll
            for (int off = 32; off; off >>= 1) v += __shfl_down(v, off, 64);
            if ((tid & 63) == 0) red[16 + (tid >> 6)] = v;
            __syncthreads();
            float ssum = ((red[16+bt*8+0] + red[16+bt*8+1]) + (red[16+bt*8+2] + red[16+bt*8+3])) +
                         ((red[16+bt*8+4] + red[16+bt*8+5]) + (red[16+bt*8+6] + red[16+bt*8+7]));
            float al = ex * fastrcp(ssum);
            awp[bt * 542 + 15 + t] = al;
            awcp[bt * 542 + 15 + t] += al;
            ntstore_f(&out[OUT_ATT + ((size_t)(blk * 2 + bt) * 100 + step) * 512 + t], al);
        }
        __syncthreads();

        // ---- R7: ctx partials per batch (512 thr each) ----
        {
            float* scrF = (float*)cbuf;   // overlay; conv data dead after R5
            const int bt = tid >> 9, r = tid & 511;
            if (big) {
                const int dg = r & 63, ts = r >> 6;     // 8 ts x 64 t, 8 halves/thread
                const uint4* ib = (const uint4*)(inF16 + ((size_t)((blk * 2 + bt) * 512) + ts * 64) * 512 + dg * 8);
                const float* alp = &awp[bt * 542 + 15 + ts * 64];
                float4 p0 = {0.f,0.f,0.f,0.f}, p1 = {0.f,0.f,0.f,0.f};
#pragma unroll 8
                for (int t = 0; t < 64; t++) {
                    float al = alp[t];
                    U4 u; u.v = ntload_u4(ib + (size_t)t * 64);
                    p0.x += al * (float)u.h[0]; p0.y += al * (float)u.h[1];
                    p0.z += al * (float)u.h[2]; p0.w += al * (float)u.h[3];
                    p1.x += al * (float)u.h[4]; p1.y += al * (float)u.h[5];
                    p1.z += al * (float)u.h[6]; p1.w += al * (float)u.h[7];
                }
                *(float4*)&scrF[bt * 4096 + ts * 512 + dg * 8] = p0;
                *(float4*)&scrF[bt * 4096 + ts * 512 + dg * 8 + 4] = p1;
            } else {
                const int dg = r & 127, ts = r >> 7;    // 4 ts x 128 t, 4 f/thread
                const float* ib = inputs + ((size_t)((blk * 2 + bt) * 512) + ts * 128) * 512;
                const float* alp = &awp[bt * 542 + 15 + ts * 128];
                float4 acc = {0.f,0.f,0.f,0.f};
#pragma unroll 8
                for (int t = 0; t < 128; t++) {
                    float al = alp[t];
                    float4 xv = ntload_f4(ib + (size_t)t * 512 + dg * 4);
                    acc.x += al * xv.x; acc.y += al * xv.y; acc.z += al * xv.z; acc.w += al * xv.w;
                }
                *(float4*)&scrF[bt * 4096 + ts * 512 + dg * 4] = acc;
            }
        }
        __syncthreads();

        // ---- R8: ctx reduce + pack pairs (512 thr = 2 bt x 256) ----
        if (tid < 512) {
            const int bt = tid >> 8, lo = tid & 255;
            const float* scrF = (const float*)cbuf;
            float s0 = 0.f, s1 = 0.f;
            if (big) {
#pragma unroll
                for (int q = 0; q < 8; q++) { s0 += scrF[bt*4096 + q*512 + 2*lo]; s1 += scrF[bt*4096 + q*512 + 2*lo + 1]; }
            } else {
#pragma unroll
                for (int q = 0; q < 4; q++) { s0 += scrF[bt*4096 + q*512 + 2*lo]; s1 += scrF[bt*4096 + q*512 + 2*lo + 1]; }
            }
            u32 pr = packh2(s0, s1);
            xpatt[bt * 320 + 64 + lo] = pr;
            xppd[bt * 384 + 128 + lo] = pr;
        }
        __syncthreads();

        // ---- R9: pd partials, both batches (1024 thr: 64 og x 16 ks) ----
        {
            const int og = tid & 63, ks = tid >> 6;
            float4 a0 = {0.f,0.f,0.f,0.f}, a1 = {0.f,0.f,0.f,0.f};
#pragma unroll 8
            for (int p = ks * 24; p < ks * 24 + 24; p++) {
                uint4 w = w_pd[p * 64 + og];
                u32 x0 = xppd[p], x1 = xppd[384 + p];
                a0.x = dot2(w.x, x0, a0.x); a0.y = dot2(w.y, x0, a0.y);
                a0.z = dot2(w.z, x0, a0.z); a0.w = dot2(w.w, x0, a0.w);
                a1.x = dot2(w.x, x1, a1.x); a1.y = dot2(w.y, x1, a1.y);
                a1.z = dot2(w.z, x1, a1.z); a1.w = dot2(w.w, x1, a1.w);
            }
            *(float4*)&scrA[ks * 256 + og * 4] = a0;
            *(float4*)&scrB[ks * 256 + og * 4] = a1;
        }
        __syncthreads();

        // ---- R10: dec combine + pack (256 thr) ----
        if (tid < 256) {
            const int bt = tid >> 7, lo = tid & 127;
            const float* P = bt ? scrB : scrA;
            float d0 = pd_b[2 * lo], d1 = pd_b[2 * lo + 1];
#pragma unroll
            for (int q = 0; q < 16; q++) { d0 += P[q * 256 + 2 * lo]; d1 += P[q * 256 + 2 * lo + 1]; }
            dec[bt * 256 + 2 * lo] = d0; dec[bt * 256 + 2 * lo + 1] = d1;
            decp[bt * 128 + lo] = packh2(d0, d1);
        }
        __syncthreads();

        // ---- R11: GRU1 partials, both batches ----
        if (tid < 768) {
            const int og = tid % 192;
            const int ks = tid / 192;
            float4 ai0 = {0.f,0.f,0.f,0.f}, ai1 = {0.f,0.f,0.f,0.f};
            float4 ah0 = {0.f,0.f,0.f,0.f}, ah1 = {0.f,0.f,0.f,0.f};
#pragma unroll 8
            for (int p = ks * 32; p < ks * 32 + 32; p++) {
                uint4 w1 = w_d1ih[p * 192 + og];
                uint4 w2 = w_d1hh[p * 192 + og];
                u32 xd0 = decp[p], xd1 = decp[128 + p];
                u32 xh0 = h1p[p],  xh1 = h1p[128 + p];
                ai0.x = dot2(w1.x, xd0, ai0.x); ai0.y = dot2(w1.y, xd0, ai0.y);
                ai0.z = dot2(w1.z, xd0, ai0.z); ai0.w = dot2(w1.w, xd0, ai0.w);
                ai1.x = dot2(w1.x, xd1, ai1.x); ai1.y = dot2(w1.y, xd1, ai1.y);
                ai1.z = dot2(w1.z, xd1, ai1.z); ai1.w = dot2(w1.w, xd1, ai1.w);
                ah0.x = dot2(w2.x, xh0, ah0.x); ah0.y = dot2(w2.y, xh0, ah0.y);
                ah0.z = dot2(w2.z, xh0, ah0.z); ah0.w = dot2(w2.w, xh0, ah0.w);
                ah1.x = dot2(w2.x, xh1, ah1.x); ah1.y = dot2(w2.y, xh1, ah1.y);
                ah1.z = dot2(w2.z, xh1, ah1.z); ah1.w = dot2(w2.w, xh1, ah1.w);
            }
            *(float4*)&scrA[ks * 768 + og * 4] = ai0;
            *(float4*)&scrB[ks * 768 + og * 4] = ai1;
            *(float4*)&scrH[ks * 768 + og * 4] = ah0;
            *(float4*)&scrH[3072 + ks * 768 + og * 4] = ah1;
        }
        __syncthreads();

        // ---- R12: GRU1 combine + residual + pack (256 thr) ----
        if (tid < 256) {
            const int bt = tid >> 7, lo = tid & 127;
            const float* P = bt ? scrB : scrA;
            const float* H = scrH + bt * 3072;
            float hv[2], dv[2];
#pragma unroll
            for (int j = 0; j < 2; j++) {
                const int o = lo * 2 + j;
                float gr = d1b_ih[o], gz = d1b_ih[256 + o], gn = d1b_ih[512 + o];
                float hr = d1b_hh[o], hz = d1b_hh[256 + o], hn = d1b_hh[512 + o];
#pragma unroll
                for (int s = 0; s < 4; s++) {
                    gr += P[s * 768 + o]; gz += P[s * 768 + 256 + o]; gn += P[s * 768 + 512 + o];
                    hr += H[s * 768 + o]; hz += H[s * 768 + 256 + o]; hn += H[s * 768 + 512 + o];
                }
                float r = sig_p(gr + hr), z = sig_p(gz + hz);
                float n = tanh_f(gn + r * hn);
                hv[j] = (1.f - z) * n + z * h1[bt * 256 + o];
                h1[bt * 256 + o] = hv[j];
                dv[j] = hv[j] + dec[bt * 256 + o];
                dec[bt * 256 + o] = dv[j];
            }
            h1p[bt * 128 + lo] = packh2(hv[0], hv[1]);
            decp[bt * 128 + lo] = packh2(dv[0], dv[1]);
        }
        __syncthreads();

        // ---- R13: GRU2 partials, both batches ----
        if (tid < 768) {
            const int og = tid % 192;
            const int ks = tid / 192;
            float4 ai0 = {0.f,0.f,0.f,0.f}, ai1 = {0.f,0.f,0.f,0.f};
            float4 ah0 = {0.f,0.f,0.f,0.f}, ah1 = {0.f,0.f,0.f,0.f};
#pragma unroll 8
            for (int p = ks * 32; p < ks * 32 + 32; p++) {
                uint4 w1 = w_d2ih[p * 192 + og];
                uint4 w2 = w_d2hh[p * 192 + og];
                u32 xd0 = decp[p], xd1 = decp[128 + p];
                u32 xh0 = h2p[p],  xh1 = h2p[128 + p];
                ai0.x = dot2(w1.x, xd0, ai0.x); ai0.y = dot2(w1.y, xd0, ai0.y);
                ai0.z = dot2(w1.z, xd0, ai0.z); ai0.w = dot2(w1.w, xd0, ai0.w);
                ai1.x = dot2(w1.x, xd1, ai1.x); ai1.y = dot2(w1.y, xd1, ai1.y);
                ai1.z = dot2(w1.z, xd1, ai1.z); ai1.w = dot2(w1.w, xd1, ai1.w);
                ah0.x = dot2(w2.x, xh0, ah0.x); ah0.y = dot2(w2.y, xh0, ah0.y);
                ah0.z = dot2(w2.z, xh0, ah0.z); ah0.w = dot2(w2.w, xh0, ah0.w);
                ah1.x = dot2(w2.x, xh1, ah1.x); ah1.y = dot2(w2.y, xh1, ah1.y);
                ah1.z = dot2(w2.z, xh1, ah1.z); ah1.w = dot2(w2.w, xh1, ah1.w);
            }
            *(float4*)&scrA[ks * 768 + og * 4] = ai0;
            *(float4*)&scrB[ks * 768 + og * 4] = ai1;
            *(float4*)&scrH[ks * 768 + og * 4] = ah0;
            *(float4*)&scrH[3072 + ks * 768 + og * 4] = ah1;
        }
        __syncthreads();

        // ---- R14: GRU2 combine + residual + pack (256 thr) ----
        if (tid < 256) {
            const int bt = tid >> 7, lo = tid & 127;
            const float* P = bt ? scrB : scrA;
            const float* H = scrH + bt * 3072;
            float hv[2], dv[2];
#pragma unroll
            for (int j = 0; j < 2; j++) {
                const int o = lo * 2 + j;
                float gr = d2b_ih[o], gz = d2b_ih[256 + o], gn = d2b_ih[512 + o];
                float hr = d2b_hh[o], hz = d2b_hh[256 + o], hn = d2b_hh[512 + o];
#pragma unroll
                for (int s = 0; s < 4; s++) {
                    gr += P[s * 768 + o]; gz += P[s * 768 + 256 + o]; gn += P[s * 768 + 512 + o];
                    hr += H[s * 768 + o]; hz += H[s * 768 + 256 + o]; hn += H[s * 768 + 512 + o];
                }
                float r = sig_p(gr + hr), z = sig_p(gz + hz);
                float n = tanh_f(gn + r * hn);
                hv[j] = (1.f - z) * n + z * h2[bt * 256 + o];
                h2[bt * 256 + o] = hv[j];
                dv[j] = hv[j] + dec[bt * 256 + o];
                dec[bt * 256 + o] = dv[j];
            }
            h2p[bt * 128 + lo] = packh2(hv[0], hv[1]);
            decp[bt * 128 + lo] = packh2(dv[0], dv[1]);
        }
        __syncthreads();

        // ---- R15: mel partials, both batches (560 thr: 140 og x 4 ks) ----
        if (tid < 560) {
            const int og = tid % 140;
            const int ks = tid / 140;
            float4 a0 = {0.f,0.f,0.f,0.f}, a1 = {0.f,0.f,0.f,0.f};
#pragma unroll 8
            for (int p = ks * 32; p < ks * 32 + 32; p++) {
                uint4 w = w_mel[p * 140 + og];
                u32 x0 = decp[p], x1 = decp[128 + p];
                a0.x = dot2(w.x, x0, a0.x); a0.y = dot2(w.y, x0, a0.y);
                a0.z = dot2(w.z, x0, a0.z); a0.w = dot2(w.w, x0, a0.w);
                a1.x = dot2(w.x, x1, a1.x); a1.y = dot2(w.y, x1, a1.y);
                a1.z = dot2(w.z, x1, a1.z); a1.w = dot2(w.w, x1, a1.w);
            }
            *(float4*)&scrA[ks * 560 + og * 4] = a0;
            *(float4*)&scrB[ks * 560 + og * 4] = a1;
        }
        __syncthreads();

        // ---- R16: mel reduce + output (560 thr = 2 bt x 280) ----
        if (tid < 560) {
            const int bt = (tid >= 280) ? 1 : 0;
            const int lo = bt ? (tid - 280) : tid;
            const float* P = bt ? scrB : scrA;
#pragma unroll
            for (int j = 0; j < 2; j++) {
                const int o = 2 * lo + j;
                float m = mel_b[o];
#pragma unroll
                for (int s = 0; s < 4; s++) m += P[s * 560 + o];
                mout[bt * 560 + o] = m;
                if (big) {
                    mstage[((size_t)(blk * 2 + bt) * 100 + step) * 560 + o] = m;
                } else {
                    int mm = o % 80, jj = o / 80;
                    out[((size_t)(blk * 2 + bt) * 80 + mm) * 700 + 7 * step + jj] = m;
                }
            }
        }
        __syncthreads();

        // ---- R17: stop tokens (both batches) || p2 prefetch ----
        {
            float v0 = 0.f, v1 = 0.f;
            if (tid < 816) {
                float w = stop_w[tid];
                if (tid < 256) { v0 = dec[tid] * w; v1 = dec[256 + tid] * w; }
                else { v0 = mout[tid - 256] * w; v1 = mout[560 + tid - 256] * w; }
            }
            if (tid < 832) {
#pragma unroll
                for (int off = 32; off; off >>= 1) {
                    v0 += __shfl_down(v0, off, 64);
                    v1 += __shfl_down(v1, off, 64);
                }
                if ((tid & 63) == 0) { red[tid >> 6] = v0; red[16 + (tid >> 6)] = v1; }
            }
            if (tid >= 960 && step + 1 < NSTEP) {
                int j = tid - 960;
                const float* p2n = p2all + ((size_t)(step + 1) * 64 + blk * 2) * 128;
                xpatt[j]       = packh2(ntload_f(p2n + 2 * j), ntload_f(p2n + 2 * j + 1));
                xpatt[320 + j] = packh2(ntload_f(p2n + 128 + 2 * j), ntload_f(p2n + 128 + 2 * j + 1));
            }
        }
        __syncthreads();
        if (tid == 0) {
            float s0 = sb0, s1 = sb0;
            for (int w = 0; w < 13; w++) { s0 += red[w]; s1 += red[16 + w]; }
            ntstore_f(&out[OUT_STOP + (size_t)(blk * 2) * 100 + step], s0);
            ntstore_f(&out[OUT_STOP + (size_t)(blk * 2 + 1) * 100 + step], s1);
        }
        // no tail barrier: next R1 touches scrA/scrB/scrH (all fenced above;
        // cbuf's R7 overlay is dead after R8), xpatt written pre-barrier,
        // xppd stable since R2/R8; red next written in R6.
    }
}

extern "C" void kernel_launch(void* const* d_in, const int* in_sizes, int n_in,
                              void* d_out, int out_size, void* d_ws, size_t ws_size,
                              hipStream_t stream) {
    const float* inputs    = (const float*)d_in[0];
    const float* memory    = (const float*)d_in[1];
    const float* prenet_w1 = (const float*)d_in[3];
    const float* prenet_b1 = (const float*)d_in[4];
    const float* prenet_w2 = (const float*)d_in[5];
    const float* prenet_b2 = (const float*)d_in[6];
    const float* att_w_ih  = (const float*)d_in[7];
    const float* att_w_hh  = (const float*)d_in[8];
    const float* att_b_ih  = (const float*)d_in[9];
    const float* att_b_hh  = (const float*)d_in[10];
    const float* q_w       = (const float*)d_in[11];
    const float* inp_w     = (const float*)d_in[12];
    const float* v_w       = (const float*)d_in[13];
    const float* v_b       = (const float*)d_in[14];
    const float* loc_conv  = (const float*)d_in[15];
    const float* loc_w     = (const float*)d_in[16];
    const float* pd_w      = (const float*)d_in[17];
    const float* pd_b      = (const float*)d_in[18];
    const float* d1_w_ih   = (const float*)d_in[19];
    const float* d1_w_hh   = (const float*)d_in[20];
    const float* d1_b_ih   = (const float*)d_in[21];
    const float* d1_b_hh   = (const float*)d_in[22];
    const float* d2_w_ih   = (const float*)d_in[23];
    const float* d2_w_hh   = (const float*)d_in[24];
    const float* d2_b_ih   = (const float*)d_in[25];
    const float* d2_b_hh   = (const float*)d_in[26];
    const float* mel_w     = (const float*)d_in[27];
    const float* mel_b     = (const float*)d_in[28];
    const float* stop_w    = (const float*)d_in[29];
    const float* stop_b    = (const float*)d_in[30];

    u32* wsu = (u32*)d_ws;
    float* out = (float*)d_out;
    const int big = ws_size >= (size_t)WS_NEED_U * 4u;

    auto P = [&](const float* src, int off, int O, int K) {
        int n = O * (K / 2);
        packw<<<(n + 255) / 256, 256, 0, stream>>>(src, wsu + off, O, K);
    };
    P(att_w_ih, PK_ATTIH, 768, 640);
    P(att_w_hh, PK_ATTHH, 768, 256);
    P(q_w,      PK_Q,     128, 256);
    P(pd_w,     PK_PD,    256, 768);
    P(d1_w_ih,  PK_D1IH,  768, 256);
    P(d1_w_hh,  PK_D1HH,  768, 256);
    P(d2_w_ih,  PK_D2IH,  768, 256);
    P(d2_w_hh,  PK_D2HH,  768, 256);
    P(mel_w,    PK_MEL,   560, 256);

    // prenet weight transposes (fp32)
    tkern<<<(256 * 80 + 255) / 256, 256, 0, stream>>>(prenet_w1, (float*)(wsu + W1T_U), 256, 80);
    tkern<<<(128 * 256 + 255) / 256, 256, 0, stream>>>(prenet_w2, (float*)(wsu + W2T_U), 128, 256);

    prenet_kern<<<6400, 256, 0, stream>>>(memory, (float*)(wsu + W1T_U), prenet_b1,
                                          (float*)(wsu + W2T_U), prenet_b2,
                                          (float*)(wsu + P2ALL_U));

    {
        float* inpT = (float*)(wsu + INPT_U);
        tkern<<<(128 * 512 + 255) / 256, 256, 0, stream>>>(inp_w, inpT, 128, 512);
        proc_kern<<<4096, 1024, 0, stream>>>(inputs, inpT, (_Float16*)(wsu + PROCF_U));
    }

    if (big) packi<<<32768, 256, 0, stream>>>(inputs, wsu + INF16_U);

    // transposed loc_conv table into the (now dead) inpT region
    tlcg<<<8, 256, 0, stream>>>(loc_conv, (float*)(wsu + INPT_U));

    decoder_kern<<<32, 1024, 0, stream>>>(inputs, wsu,
                                          att_b_ih, att_b_hh, v_w, v_b,
                                          (const float*)(wsu + INPT_U), loc_w, pd_b,
                                          d1_b_ih, d1_b_hh, d2_b_ih, d2_b_hh,
                                          mel_b, stop_w, stop_b, out, big);

    if (big) unmel<<<14000, 256, 0, stream>>>((const float*)(wsu + MSTG_U), out);
}